// Round 16
// baseline (6538.806 us; speedup 1.0000x reference)
//
#include <hip/hip_runtime.h>
#include <hip/hip_bf16.h>
#include <cstdint>
#include <cstddef>

#define NB 4
#define N_PTS 16384
#define M_FIX 256
#define P_ALL 16640
#define S_TOT 2304
#define NPT 2048
#define KNB 64
#define CH1 128
#define CH3 256
#define NRED 589824.0f
#define ZPB (P_ALL / 64)   // 260 zp tiles per batch
#define WTS 133            // w_t stride: (5c+o)&31 bijective => conflict-free writes

typedef float v2f __attribute__((ext_vector_type(2)));

// d_out offsets (float elements)
#define OUT_XYZ 0
#define OUT_FEAT 27648
#define OUT_INDS 2386944

// workspace offsets (bytes) -- total 39,481,344 B (~37.7 MB)
#define OFF_ALLX   0ull           // 4*16640*3*4 = 798720
#define OFF_STATS  798720ull      // 65536*4     = 262144
#define OFF_BN     1060864ull     // 1024*4      = 4096
#define OFF_MAXZ   1064960ull     // 9437184
#define OFF_MINZ   10502144ull    // 9437184
#define OFF_IDX    19939328ull    // 4*2304*64*4 = 2359296
#define OFF_ZP     22298624ull    // bf16 4*16640*128*2 = 17039360
#define OFF_NEWX   39337984ull    // 4*2304*3*4  = 110592
#define OFF_INDSI  39448576ull    // 4*2048*4    = 32768
// FPS scratch OVERLAPS the maxz region (maxz only written by k_layer3,
// long after k_fps finishes):
#define OFF_HIST   1064960ull     // 4*512*4 = 8192
#define OFF_OFFS   1073152ull     // 8192
#define OFF_SX     1081344ull     // 4*16384*4 = 262144
#define OFF_SY     1343488ull
#define OFF_SZ     1605632ull
#define OFF_SIDX   1867776ull     // end 2129920
#define OFF_XYZ4   2129920ull     // 4*16384*16 = 1048576, end 3178496 (< maxz end)

// ---------------------------------------------------------------- helpers
__device__ __forceinline__ float red16s(float v) {
  v += __shfl_xor(v, 1); v += __shfl_xor(v, 2);
  v += __shfl_xor(v, 4); v += __shfl_xor(v, 8);
  return v;
}
__device__ __forceinline__ float red16mx(float v) {
  v = fmaxf(v, __shfl_xor(v, 1)); v = fmaxf(v, __shfl_xor(v, 2));
  v = fmaxf(v, __shfl_xor(v, 4)); v = fmaxf(v, __shfl_xor(v, 8));
  return v;
}
__device__ __forceinline__ float red16mn(float v) {
  v = fminf(v, __shfl_xor(v, 1)); v = fminf(v, __shfl_xor(v, 2));
  v = fminf(v, __shfl_xor(v, 4)); v = fminf(v, __shfl_xor(v, 8));
  return v;
}
__device__ __forceinline__ float xyzp(float dx, float dy, float dz,
                                      float wx, float wy, float wz) {
  return fmaf(dx, wx, fmaf(dy, wy, __fmul_rn(dz, wz)));
}
__device__ __forceinline__ int mort3(int v) {
  return (v & 1) | ((v & 2) << 1) | ((v & 4) << 2);
}
__device__ __forceinline__ int cell_code(float x, float y, float z) {
  int cx = min(7, max(0, (int)(x * 8.0f)));
  int cy = min(7, max(0, (int)(y * 8.0f)));
  int cz = min(7, max(0, (int)(z * 8.0f)));
  return mort3(cx) | (mort3(cy) << 1) | (mort3(cz) << 2);
}

// u64 max with a DPP-shifted copy (VALU-pipe latency, no LDS round-trip).
// bound_ctrl=false + old=self => masked/invalid lanes are identity for max.
template <int CTRL, int RM>
__device__ __forceinline__ unsigned long long dppmax(unsigned long long k) {
  int lo = (int)(unsigned)(k & 0xFFFFFFFFull);
  int hi = (int)(unsigned)(k >> 32);
  int sl = __builtin_amdgcn_update_dpp(lo, lo, CTRL, RM, 0xF, false);
  int sh = __builtin_amdgcn_update_dpp(hi, hi, CTRL, RM, 0xF, false);
  unsigned long long s = ((unsigned long long)(unsigned)sh << 32) | (unsigned)sl;
  return (s > k) ? s : k;
}
// full wave64 max-reduce -> valid in lane 63
__device__ __forceinline__ unsigned long long wave_max64(unsigned long long k) {
  k = dppmax<0x111, 0xF>(k);  // row_shr:1
  k = dppmax<0x112, 0xF>(k);  // row_shr:2
  k = dppmax<0x114, 0xF>(k);  // row_shr:4
  k = dppmax<0x118, 0xF>(k);  // row_shr:8
  k = dppmax<0x142, 0xa>(k);  // row_bcast:15 -> rows 1,3
  k = dppmax<0x143, 0xc>(k);  // row_bcast:31 -> rows 2,3
  return k;
}
// 16-lane row max-reduce -> valid in lane 15 of each row
__device__ __forceinline__ unsigned long long row_max64(unsigned long long k) {
  k = dppmax<0x111, 0xF>(k);
  k = dppmax<0x112, 0xF>(k);
  k = dppmax<0x114, 0xF>(k);
  k = dppmax<0x118, 0xF>(k);
  return k;
}

// ---------------------------------------------------------------- build arrays
// R13: k_cell folded in (hist zeroed by hipMemsetAsync before this dispatch).
__global__ void k_build(const float* __restrict__ fixed, const float* __restrict__ xyz,
                        float* __restrict__ allx, float* __restrict__ newx,
                        float* __restrict__ stats, int* __restrict__ inds_i,
                        int* __restrict__ hist, float4* __restrict__ xyz4) {
  int i = blockIdx.x * 256 + threadIdx.x;
  if (i < NB * P_ALL * 3) {
    int b = i / (P_ALL * 3);
    int r = i % (P_ALL * 3);
    int p = r / 3, c = r % 3;
    float v = (p < M_FIX) ? fixed[((size_t)b * M_FIX + p) * 3 + c]
                          : xyz[((size_t)b * N_PTS + (p - M_FIX)) * 3 + c];
    allx[i] = v;
  }
  if (i < NB * N_PTS) {
    const float* pt = xyz + (size_t)i * 3;
    float x = pt[0], y = pt[1], z = pt[2];
    xyz4[i] = make_float4(x, y, z, 0.f);
    int b = i >> 14;
    int code = cell_code(x, y, z);
    atomicAdd(&hist[(b << 9) + code], 1);
  }
  if (i < NB * M_FIX * 3) {
    int b = i / (M_FIX * 3);
    int r = i % (M_FIX * 3);
    newx[(size_t)b * S_TOT * 3 + r] = fixed[(size_t)b * M_FIX * 3 + r];
  }
  if (i < 65536) stats[i] = 0.0f;
  if (i < NB) inds_i[(size_t)i * NPT] = 0;
}

__global__ __launch_bounds__(512) void k_scan(const int* __restrict__ hist,
                                              int* __restrict__ offs) {
  __shared__ int tmp[512];
  int b = blockIdx.x, t = threadIdx.x;
  int h = hist[(b << 9) + t];
  tmp[t] = h;
  __syncthreads();
  for (int o = 1; o < 512; o <<= 1) {
    int v = (t >= o) ? tmp[t - o] : 0;
    __syncthreads();
    tmp[t] += v;
    __syncthreads();
  }
  offs[(b << 9) + t] = tmp[t] - h;  // exclusive
}

// R13: reads coalesced xyz4 (bit-identical values).
__global__ void k_scatter(const float4* __restrict__ xyz4, int* __restrict__ offs,
                          float* __restrict__ sx, float* __restrict__ sy,
                          float* __restrict__ sz, int* __restrict__ sidx) {
  int i = blockIdx.x * 256 + threadIdx.x;
  int b = i >> 14, p = i & 16383;
  float4 pt = xyz4[i];
  float x = pt.x, y = pt.y, z = pt.z;
  int code = cell_code(x, y, z);
  int pos = atomicAdd(&offs[(b << 9) + code], 1);
  int o = (b << 14) + pos;
  sx[o] = x; sy[o] = y; sz[o] = z; sidx[o] = p;
}

// ---------------------------------------------------------------- FPS + zp (fused)
// FPS path: R10/R8 two-barrier shape, permanently frozen. zp fused (R10 win).
// R14/R16: zp w_t stride WTS=133 (conflict-free LDS writes; verified in R15:
// SQ_LDS_BANK_CONFLICT 1.6M -> 0, zp still hidden under FPS).
__global__ __launch_bounds__(1024, 4) void k_fps(const float4* __restrict__ xyz4,
                                                 const float* __restrict__ sx,
                                                 const float* __restrict__ sy,
                                                 const float* __restrict__ sz,
                                                 const int* __restrict__ sidx,
                                                 float* __restrict__ newx,
                                                 int* __restrict__ inds_i,
                                                 const float* __restrict__ feats,
                                                 const float* __restrict__ W1,
                                                 __hip_bfloat16* __restrict__ zp) {
  __shared__ __align__(16) float smem[CH1 * 68 + 32 * WTS];  // 51840 B
  int t = threadIdx.x;

  if (blockIdx.x >= NB) {
    // ---------------- zp path: one 64-point tile, 1024 threads ----------------
    int bz = blockIdx.x - NB;
    int b = bz / ZPB;
    int p0 = (bz % ZPB) * 64;
    float* a_t = smem;
    float* w_t = smem + CH1 * 68;
    for (int r = t; r < CH1 * 64; r += 1024) {
      int c = r >> 6, p = r & 63;
      a_t[c * 68 + p] = feats[((size_t)b * CH1 + c) * P_ALL + p0 + p];
    }
    int tk = t & 63, to = t >> 6;  // point row 0..63, output group 0..15
    v2f acc[4];
#pragma unroll
    for (int p = 0; p < 4; ++p) acc[p] = (v2f){0.f, 0.f};
    const float* Wg = W1 + 3;  // ldw 131
    for (int c0 = 0; c0 < CH1; c0 += 32) {
      __syncthreads();  // first iter: a_t staged; later: prev compute done
      for (int r = t; r < 32 * 128; r += 1024) {
        int c = r & 31, o = r >> 5;  // c-major: coalesced W rows
        w_t[c * WTS + o] = Wg[(size_t)o * 131 + (c0 + c)];
      }
      __syncthreads();
#pragma unroll 4
      for (int c = 0; c < 32; ++c) {
        float a = a_t[(c0 + c) * 68 + tk];       // lane-striped, 2-way free
        v2f w2[4];                               // wave-uniform broadcast reads
        *(float4*)&w2[0] = *(const float4*)&w_t[c * WTS + to * 8];
        *(float4*)&w2[2] = *(const float4*)&w_t[c * WTS + to * 8 + 4];
        v2f a2 = {a, a};
#pragma unroll
        for (int p = 0; p < 4; ++p)
          acc[p] = __builtin_elementwise_fma(a2, w2[p], acc[p]);
      }
    }
    union { __hip_bfloat16 h[8]; uint4 u; } tmp;
#pragma unroll
    for (int j = 0; j < 8; ++j)
      tmp.h[j] = __float2bfloat16((j & 1) ? acc[j >> 1].y : acc[j >> 1].x);
    *(uint4*)&zp[((size_t)b * P_ALL + p0 + tk) * CH1 + to * 8] = tmp.u;
    return;
  }

  // ---------------- FPS path (blocks 0..NB-1), R10/R8 two-barrier shape ------
  unsigned long long* red = (unsigned long long*)smem;     // 16 u64
  float4* wcoord = (float4*)(smem + 32);                   // 16 float4
  float4* s_win = (float4*)(smem + 96);                    // 1 float4
  int* idxbuf = (int*)(smem + 100);                        // NPT ints

  int b = blockIdx.x;
  const float4* bx4 = xyz4 + (size_t)b * N_PTS;
  int off0 = (b << 14) + (t << 4);
  v2f px2[8], py2[8], pz2[8];
  float dist[16];
  unsigned npidp[8];  // packed 16-bit keys: 16383 - orig_idx
#pragma unroll
  for (int u = 0; u < 8; ++u) {
    px2[u] = *(const v2f*)&sx[off0 + 2 * u];
    py2[u] = *(const v2f*)&sy[off0 + 2 * u];
    pz2[u] = *(const v2f*)&sz[off0 + 2 * u];
    dist[2 * u] = 1e10f; dist[2 * u + 1] = 1e10f;
  }
#pragma unroll
  for (int u = 0; u < 8; ++u) {
    unsigned a = 16383u - (unsigned)sidx[off0 + 2 * u];
    unsigned c = 16383u - (unsigned)sidx[off0 + 2 * u + 1];
    npidp[u] = a | (c << 16);
  }
  float xmn = px2[0].x, xmx = px2[0].x, ymn = py2[0].x, ymx = py2[0].x;
  float zmn = pz2[0].x, zmx = pz2[0].x;
#pragma unroll
  for (int u = 0; u < 8; ++u) {
    xmn = fminf(xmn, fminf(px2[u].x, px2[u].y));
    xmx = fmaxf(xmx, fmaxf(px2[u].x, px2[u].y));
    ymn = fminf(ymn, fminf(py2[u].x, py2[u].y));
    ymx = fmaxf(ymx, fmaxf(py2[u].x, py2[u].y));
    zmn = fminf(zmn, fminf(pz2[u].x, pz2[u].y));
    zmx = fmaxf(zmx, fmaxf(pz2[u].x, pz2[u].y));
  }
  float cx = (xmn + xmx) * 0.5f, cy = (ymn + ymx) * 0.5f, cz = (zmn + zmx) * 0.5f;
  float r2m = 0.f;
#pragma unroll
  for (int u = 0; u < 8; ++u) {
#pragma unroll
    for (int h = 0; h < 2; ++h) {
      float ax = (h ? px2[u].y : px2[u].x) - cx;
      float ay = (h ? py2[u].y : py2[u].x) - cy;
      float az = (h ? pz2[u].y : pz2[u].x) - cz;
      r2m = fmaxf(r2m, ax * ax + ay * ay + az * az);
    }
  }
  float rad = sqrtf(r2m) + 2e-3f;  // slack >> fp32 rounding
  float4 p0 = bx4[0];
  float lx = p0.x, ly = p0.y, lz = p0.z;
  if (t == 0) {
    size_t nb0 = ((size_t)b * S_TOT + M_FIX) * 3;
    newx[nb0] = lx; newx[nb0 + 1] = ly; newx[nb0 + 2] = lz;
  }
  unsigned long long bestkey = 0ull;
  unsigned long long kprev = ~0ull;  // sentinel: never equals a real key
  float thr = 3.4e38f;  // first iteration: everyone active
  int lane = t & 63, wid = t >> 6;
  for (int iter = 1; iter < NPT; ++iter) {
    float ex = lx - cx, ey = ly - cy, ez = lz - cz;
    bool active = (ex * ex + ey * ey + ez * ez) < thr;
    if (__ballot(active) != 0ull) {  // wave-uniform
      // pass 1: exact distance update + per-thread change flag.
      bool ch = false;
      if (active) {
#pragma clang fp contract(off)
        v2f l2x = {lx, lx}, l2y = {ly, ly}, l2z = {lz, lz};
#pragma unroll
        for (int u = 0; u < 8; ++u) {
          v2f dx = px2[u] - l2x;
          v2f dy = py2[u] - l2y;
          v2f dz = pz2[u] - l2z;
          v2f xx = dx * dx;
          v2f yy = dy * dy;
          v2f zz = dz * dz;
          v2f d2 = (xx + yy) + zz;
          if (d2.x < dist[2 * u])     { dist[2 * u] = d2.x;     ch = true; }
          if (d2.y < dist[2 * u + 1]) { dist[2 * u + 1] = d2.y; ch = true; }
        }
      }
      // pass 2: key rebuild + reduce, only if some lane actually changed.
      // Skipped => bestkey/thr/red[wid]/wcoord[wid] all provably unchanged.
      if (__ballot(ch) != 0ull) {  // wave-uniform
        if (ch) {
          unsigned long long c0 = 0ull, c1 = 0ull, c2 = 0ull, c3 = 0ull;
#pragma unroll
          for (int j = 0; j < 16; ++j) {
            unsigned lo16 = (j & 1) ? (npidp[j >> 1] >> 16) : (npidp[j >> 1] & 0xFFFFu);
            unsigned long long kj =
                ((unsigned long long)__float_as_uint(dist[j]) << 32) | lo16;
            if ((j & 3) == 0) c0 = (kj > c0) ? kj : c0;
            else if ((j & 3) == 1) c1 = (kj > c1) ? kj : c1;
            else if ((j & 3) == 2) c2 = (kj > c2) ? kj : c2;
            else c3 = (kj > c3) ? kj : c3;
          }
          c0 = (c1 > c0) ? c1 : c0;
          c2 = (c3 > c2) ? c3 : c2;
          bestkey = (c2 > c0) ? c2 : c0;
          float ub = __uint_as_float((unsigned)(bestkey >> 32));
          float tq = sqrtf(ub) + rad;
          thr = tq * tq;
        }
        unsigned long long k = wave_max64(bestkey);
        unsigned long long kall = __shfl(k, 63);
        // Owner resolves coords into the per-wave LDS slot only when the
        // wave's max actually changed (kall wave-uniform => uniform branch).
        if (kall != kprev) {
          if (bestkey == kall) {
            unsigned lo = (unsigned)(kall & 0xFFFFull);
            float wx = 0.f, wy = 0.f, wz = 0.f;
#pragma unroll
            for (int u = 0; u < 8; ++u) {
              unsigned pk = npidp[u];
              if ((pk & 0xFFFFu) == lo) { wx = px2[u].x; wy = py2[u].x; wz = pz2[u].x; }
              if ((pk >> 16) == lo)     { wx = px2[u].y; wy = py2[u].y; wz = pz2[u].y; }
            }
            wcoord[wid] = make_float4(wx, wy, wz, 0.f);
          }
          kprev = kall;
        }
        if (lane == 63) red[wid] = k;
      }
    }
    __syncthreads();
    if (wid == 0) {
      unsigned long long wk = red[lane & 15];
      unsigned long long wr = row_max64(wk);
      unsigned long long wmax = __shfl(wr, 15);
      unsigned long long mb = __ballot(wk == wmax) & 0xFFFFull;
      int src = __ffsll(mb) - 1;  // unique (keys unique)
      if (lane == 15) {
        *s_win = wcoord[src];
        idxbuf[iter] = 16383 - (int)(wmax & 0xFFFFull);
      }
    }
    __syncthreads();
    float4 wv = *s_win;
    lx = wv.x; ly = wv.y; lz = wv.z;
  }
  __syncthreads();
  for (int s = t; s < NPT; s += 1024) {
    if (s == 0) continue;
    int wi = idxbuf[s];
    float4 wp = bx4[wi];
    inds_i[(size_t)b * NPT + s] = wi;
    size_t nb2 = ((size_t)b * S_TOT + M_FIX + s) * 3;
    newx[nb2] = wp.x; newx[nb2 + 1] = wp.y; newx[nb2 + 2] = wp.z;
  }
}

// ---------------------------------------------------------------- ball query + BN1 stats (fused)
// R12: stats1 fused (WIN). Even/odd-k partial sums kept separate and added
// once at the end -- exactly reproduces stats1's two-group reduction =>
// bit-identical atomicAdd addends.
__global__ __launch_bounds__(256) void k_ball(const float* __restrict__ allx,
                                              const float* __restrict__ newx,
                                              const float* __restrict__ W1,
                                              const __hip_bfloat16* __restrict__ zp,
                                              int* __restrict__ idx,
                                              float* __restrict__ sSum,
                                              float* __restrict__ sSq) {
  __shared__ int s_pid[4][KNB];
  int wid = threadIdx.x >> 6, lane = threadIdx.x & 63;
  int q = blockIdx.x * 4 + wid;  // 0..9215
  int b = q / S_TOT;
  const float* qp = newx + (size_t)q * 3;
  float qx = qp[0], qy = qp[1], qz = qp[2];
  const float* pts = allx + (size_t)b * P_ALL * 3;
  int* outp = idx + (size_t)q * KNB;
  const float R2 = 0.04f;
  int collected = 0;
  int first_hit = 0;
  for (int ch = 0; ch < P_ALL / 64; ++ch) {
    int p = ch * 64 + lane;
    float x = pts[p * 3 + 0], y = pts[p * 3 + 1], z = pts[p * 3 + 2];
    float dx = __fsub_rn(qx, x), dy = __fsub_rn(qy, y), dz = __fsub_rn(qz, z);
    float d2 = __fadd_rn(__fadd_rn(__fmul_rn(dx, dx), __fmul_rn(dy, dy)), __fmul_rn(dz, dz));
    bool hit = d2 < R2;
    unsigned long long m = __ballot(hit);
    if (m) {
      if (collected == 0) first_hit = ch * 64 + (__ffsll((unsigned long long)m) - 1);
      if (hit) {
        int slot = collected + __popcll(m & ((1ull << lane) - 1ull));
        if (slot < KNB) { outp[slot] = p; s_pid[wid][slot] = p; }
      }
      collected += __popcll(m);
      if (collected >= KNB) break;
    }
  }
  int sl = collected + lane;
  if (sl < KNB) { outp[sl] = first_hit; s_pid[wid][sl] = first_hit; }

  // ---- fused BN1 stats ----
  int c0 = 2 * lane, c1 = 2 * lane + 1;
  float wx0 = W1[(size_t)c0 * 131 + 0], wy0 = W1[(size_t)c0 * 131 + 1],
        wz0 = W1[(size_t)c0 * 131 + 2];
  float wx1 = W1[(size_t)c1 * 131 + 0], wy1 = W1[(size_t)c1 * 131 + 1],
        wz1 = W1[(size_t)c1 * 131 + 2];
  const uint16_t* zpb = (const uint16_t*)zp + (size_t)b * P_ALL * CH1;
  float se0 = 0.f, so0 = 0.f, se1 = 0.f, so1 = 0.f;
  float se0q = 0.f, so0q = 0.f, se1q = 0.f, so1q = 0.f;
#pragma unroll 2
  for (int k = 0; k < KNB; ++k) {
    int pid = s_pid[wid][k];
    const float* pp = pts + (size_t)pid * 3;
    float dxk = __fmul_rn(__fsub_rn(pp[0], qx), 5.0f);
    float dyk = __fmul_rn(__fsub_rn(pp[1], qy), 5.0f);
    float dzk = __fmul_rn(__fsub_rn(pp[2], qz), 5.0f);
    uint32_t w = *(const uint32_t*)(zpb + (size_t)pid * CH1 + c0);
    float v0 = __uint_as_float(w << 16);
    float v1 = __uint_as_float(w & 0xFFFF0000u);
    v0 += xyzp(dxk, dyk, dzk, wx0, wy0, wz0);
    v1 += xyzp(dxk, dyk, dzk, wx1, wy1, wz1);
    if (k & 1) {
      so0 += v0; so0q = fmaf(v0, v0, so0q);
      so1 += v1; so1q = fmaf(v1, v1, so1q);
    } else {
      se0 += v0; se0q = fmaf(v0, v0, se0q);
      se1 += v1; se1q = fmaf(v1, v1, se1q);
    }
  }
  int slot = q & 63;
  atomicAdd(&sSum[slot * CH1 + c0], se0 + so0);
  atomicAdd(&sSq[slot * CH1 + c0], se0q + so0q);
  atomicAdd(&sSum[slot * CH1 + c1], se1 + so1);
  atomicAdd(&sSq[slot * CH1 + c1], se1q + so1q);
}

// ---------------------------------------------------------------- GEMM helper
// block tile: 64(k) x 128(o), 256 threads = 16(tk) x 16(to), 4x8 regs/thread.
// R9: packed v_pk_fma_f32 accumulators (bit-identical).
// R13: W staging c-major (coalesced: 2 cache lines/wave-load vs 64). WIN.
// R14's register-staged prefetch REVERTED (R15: 3x layer slowdown -- wr[16]
// live across the unrolled FMA loop spilled to scratch). Keeping only the
// WTS=133 stride (R15-verified: bank conflicts 1.6M -> 0, no downside).
__device__ __forceinline__ void gemm_chunks(const float* a_t, float* w_t,
                                            const float* __restrict__ Wg, int K,
                                            int obase, int ldw, int tid,
                                            v2f acc[4][4]) {
  int tk = tid & 15, to = tid >> 4;
  for (int c0 = 0; c0 < K; c0 += 32) {
    __syncthreads();
    for (int r = tid; r < 32 * 128; r += 256) {
      int c = r & 31, o = r >> 5;
      w_t[c * WTS + o] = Wg[(size_t)(obase + o) * ldw + (c0 + c)];
    }
    __syncthreads();
#pragma unroll 4
    for (int c = 0; c < 32; ++c) {
      float a4[4];
      v2f w2[4];
      *(float4*)a4 = *(const float4*)&a_t[(c0 + c) * 68 + tk * 4];
      *(float4*)&w2[0] = *(const float4*)&w_t[c * WTS + to * 8];
      *(float4*)&w2[2] = *(const float4*)&w_t[c * WTS + to * 8 + 4];
#pragma unroll
      for (int i = 0; i < 4; ++i) {
        v2f a2 = {a4[i], a4[i]};
#pragma unroll
        for (int p = 0; p < 4; ++p)
          acc[i][p] = __builtin_elementwise_fma(a2, w2[p], acc[i][p]);
      }
    }
  }
}
// extract output j (0..7) of row i from the packed accumulator
#define ACC_J(acc, i, j) (((j) & 1) ? acc[i][(j) >> 1].y : acc[i][(j) >> 1].x)

// ---------------------------------------------------------------- geometry staging
__device__ __forceinline__ void stage_geom(int bs, int b, const int* __restrict__ idxg,
                                           const float* __restrict__ allx,
                                           const float* __restrict__ newx,
                                           const float* __restrict__ W1,
                                           int* s_pid, float* s_d, float* s_w1, int tid) {
  if (tid < 64) {
    int p = idxg[(size_t)bs * KNB + tid];
    s_pid[tid] = p;
    const float* pp = allx + ((size_t)b * P_ALL + p) * 3;
    const float* qq = newx + (size_t)bs * 3;
    s_d[tid]       = __fmul_rn(__fsub_rn(pp[0], qq[0]), 5.0f);
    s_d[64 + tid]  = __fmul_rn(__fsub_rn(pp[1], qq[1]), 5.0f);
    s_d[128 + tid] = __fmul_rn(__fsub_rn(pp[2], qq[2]), 5.0f);
  } else if (tid < 192) {
    int c = tid - 64;
    s_w1[c]       = W1[(size_t)c * 131 + 0];
    s_w1[128 + c] = W1[(size_t)c * 131 + 1];
    s_w1[256 + c] = W1[(size_t)c * 131 + 2];
  }
  __syncthreads();
}

// ---------------------------------------------------------------- a1 build
// R9 lane remap (k=tid&63, q=tid>>6): conflict-free a_t writes, wave-uniform
// s_w1 reads. Bit-identical a_t.
__device__ __forceinline__ void build_a1(float* a_t, const int* s_pid, const float* s_d,
                                         const float* s_w1,
                                         const __hip_bfloat16* __restrict__ zp_b,
                                         const float* __restrict__ bnS,
                                         const float* __restrict__ bnH, int tid) {
  int k = tid & 63, q = tid >> 6;
  int pid = s_pid[k];
  float dx = s_d[k], dy = s_d[64 + k], dz = s_d[128 + k];
  const uint32_t* zr = (const uint32_t*)((const uint16_t*)zp_b + (size_t)pid * CH1 + q * 32);
#pragma unroll
  for (int u = 0; u < 16; ++u) {
    uint32_t w = zr[u];
    int c = q * 32 + u * 2;
    float v0 = __uint_as_float(w << 16);
    float v1 = __uint_as_float(w & 0xFFFF0000u);
    v0 += xyzp(dx, dy, dz, s_w1[c], s_w1[128 + c], s_w1[256 + c]);
    v1 += xyzp(dx, dy, dz, s_w1[c + 1], s_w1[128 + c + 1], s_w1[256 + c + 1]);
    a_t[c * 68 + k]       = fmaxf(fmaf(v0, bnS[c], bnH[c]), 0.0f);
    a_t[(c + 1) * 68 + k] = fmaxf(fmaf(v1, bnS[c + 1], bnH[c + 1]), 0.0f);
  }
}

// ---------------------------------------------------------------- layer 2 (stats only)
__global__ __launch_bounds__(256) void k_layer2s(const int* __restrict__ idxg,
                                                 const float* __restrict__ allx,
                                                 const float* __restrict__ newx,
                                                 const float* __restrict__ W1,
                                                 const __hip_bfloat16* __restrict__ zp,
                                                 const float* __restrict__ bn1S,
                                                 const float* __restrict__ bn1H,
                                                 const float* __restrict__ W2,
                                                 float* __restrict__ sSum,
                                                 float* __restrict__ sSq) {
  __shared__ __align__(16) float smem[CH1 * 68 + 32 * WTS];
  float* a_t = smem;
  float* w_t = smem + CH1 * 68;
  int* s_pid = (int*)w_t;
  float* s_d = w_t + 64;
  float* s_w1 = w_t + 256;
  int bs = blockIdx.x;
  int b = bs / S_TOT;
  int tid = threadIdx.x;
  stage_geom(bs, b, idxg, allx, newx, W1, s_pid, s_d, s_w1, tid);
  build_a1(a_t, s_pid, s_d, s_w1, zp + (size_t)b * P_ALL * CH1, bn1S, bn1H, tid);
  v2f acc[4][4];
#pragma unroll
  for (int i = 0; i < 4; ++i)
#pragma unroll
    for (int p = 0; p < 4; ++p) acc[i][p] = (v2f){0.f, 0.f};
  gemm_chunks(a_t, w_t, W2, CH1, 0, CH1, tid, acc);
  int tk = tid & 15, to = tid >> 4;
  int slot = bs & 63;
#pragma unroll
  for (int j = 0; j < 8; ++j) {
    float s1 = 0.f, s2 = 0.f;
#pragma unroll
    for (int i = 0; i < 4; ++i) { float v = ACC_J(acc, i, j); s1 += v; s2 = fmaf(v, v, s2); }
    s1 = red16s(s1);
    s2 = red16s(s2);
    if (tk == 0) {
      int o = to * 8 + j;
      atomicAdd(&sSum[slot * CH1 + o], s1);
      atomicAdd(&sSq[slot * CH1 + o], s2);
    }
  }
}

// ---------------------------------------------------------------- layer 3
__global__ __launch_bounds__(256) void k_layer3(const int* __restrict__ idxg,
                                                const float* __restrict__ allx,
                                                const float* __restrict__ newx,
                                                const float* __restrict__ W1,
                                                const __hip_bfloat16* __restrict__ zp,
                                                const float* __restrict__ bn1S,
                                                const float* __restrict__ bn1H,
                                                const float* __restrict__ W2,
                                                const float* __restrict__ bn2S,
                                                const float* __restrict__ bn2H,
                                                const float* __restrict__ W3,
                                                float* __restrict__ maxz,
                                                float* __restrict__ minz,
                                                float* __restrict__ sSum,
                                                float* __restrict__ sSq) {
  __shared__ __align__(16) float smem[CH1 * 68 + 32 * WTS];
  float* a_t = smem;
  float* w_t = smem + CH1 * 68;
  int* s_pid = (int*)w_t;
  float* s_d = w_t + 64;
  float* s_w1 = w_t + 256;
  int bs = blockIdx.x;
  int b = bs / S_TOT;
  int tid = threadIdx.x;
  stage_geom(bs, b, idxg, allx, newx, W1, s_pid, s_d, s_w1, tid);
  build_a1(a_t, s_pid, s_d, s_w1, zp + (size_t)b * P_ALL * CH1, bn1S, bn1H, tid);
  v2f acc[4][4];
#pragma unroll
  for (int i = 0; i < 4; ++i)
#pragma unroll
    for (int p = 0; p < 4; ++p) acc[i][p] = (v2f){0.f, 0.f};
  gemm_chunks(a_t, w_t, W2, CH1, 0, CH1, tid, acc);  // acc = z2 (bit-identical to k_layer2s)
  int tk = tid & 15, to = tid >> 4;
  __syncthreads();  // all a1 reads done before overwriting a_t with a2
#pragma unroll
  for (int j = 0; j < 8; ++j) {
    int o = to * 8 + j;
    float sc = bn2S[o], sh = bn2H[o];
#pragma unroll
    for (int i = 0; i < 4; ++i)
      a_t[o * 68 + tk * 4 + i] = fmaxf(fmaf(ACC_J(acc, i, j), sc, sh), 0.0f);
  }
  int slot = bs & 63;
#pragma unroll 1
  for (int half = 0; half < 2; ++half) {
    v2f acc3[4][4];
#pragma unroll
    for (int i = 0; i < 4; ++i)
#pragma unroll
      for (int p = 0; p < 4; ++p) acc3[i][p] = (v2f){0.f, 0.f};
    gemm_chunks(a_t, w_t, W3, CH1, half * 128, CH1, tid, acc3);
#pragma unroll
    for (int j = 0; j < 8; ++j) {
      float s1 = 0.f, s2 = 0.f, mx = -3.4e38f, mn = 3.4e38f;
#pragma unroll
      for (int i = 0; i < 4; ++i) {
        float v = ACC_J(acc3, i, j);
        s1 += v; s2 = fmaf(v, v, s2);
        mx = fmaxf(mx, v); mn = fminf(mn, v);
      }
      s1 = red16s(s1);
      s2 = red16s(s2);
      mx = red16mx(mx);
      mn = red16mn(mn);
      if (tk == 0) {
        int o = half * 128 + to * 8 + j;
        atomicAdd(&sSum[slot * CH3 + o], s1);
        atomicAdd(&sSq[slot * CH3 + o], s2);
        size_t base = (size_t)bs * CH3 + o;
        maxz[base] = mx;
        minz[base] = mn;
      }
    }
  }
}

// ---------------------------------------------------------------- finalize BN
__global__ void k_fin(const float* __restrict__ sSum, const float* __restrict__ sSq,
                      const float* __restrict__ gamma, const float* __restrict__ beta,
                      float* __restrict__ bnS, float* __restrict__ bnH, int C) {
  int o = threadIdx.x;
  if (o >= C) return;
  float s1 = 0.f, s2 = 0.f;
  for (int t = 0; t < 64; ++t) { s1 += sSum[t * C + o]; s2 += sSq[t * C + o]; }
  float mean = s1 / NRED;
  float var = fmaxf(s2 / NRED - mean * mean, 0.f);
  float inv = 1.0f / sqrtf(var + 1e-5f);
  float sc = gamma[o] * inv;
  bnS[o] = sc;
  bnH[o] = beta[o] - mean * sc;
}

// ---------------------------------------------------------------- final pool
__global__ __launch_bounds__(256) void k_final(const float* __restrict__ maxz,
                                               const float* __restrict__ minz,
                                               const float* __restrict__ bnS,
                                               const float* __restrict__ bnH,
                                               float* __restrict__ out) {
  int bs = blockIdx.x;
  int o = threadIdx.x;
  float sc = bnS[o], sh = bnH[o];
  size_t base = (size_t)bs * CH3 + o;
  float v = (sc >= 0.f) ? maxz[base] : minz[base];
  float r = fmaxf(fmaf(v, sc, sh), 0.f);
  int b = bs / S_TOT, s = bs % S_TOT;
  out[OUT_FEAT + ((size_t)b * CH3 + o) * S_TOT + s] = r;
}

// ---------------------------------------------------------------- copy xyz+inds to out (last)
__global__ void k_copy(const float* __restrict__ newx, const int* __restrict__ inds_i,
                       float* __restrict__ out) {
  int i = blockIdx.x * 256 + threadIdx.x;
  if (i < NB * S_TOT * 3) out[OUT_XYZ + i] = newx[i];
  else {
    int r = i - NB * S_TOT * 3;
    if (r < NB * NPT) out[OUT_INDS + r] = (float)inds_i[r];
  }
}

// ---------------------------------------------------------------- launch
extern "C" void kernel_launch(void* const* d_in, const int* in_sizes, int n_in,
                              void* d_out, int out_size, void* d_ws, size_t ws_size,
                              hipStream_t stream) {
  const float* fixed = (const float*)d_in[0];
  const float* xyz = (const float*)d_in[1];
  const float* feats = (const float*)d_in[2];
  const float* W1 = (const float*)d_in[3];
  const float* g1 = (const float*)d_in[4];
  const float* b1 = (const float*)d_in[5];
  const float* W2 = (const float*)d_in[6];
  const float* g2 = (const float*)d_in[7];
  const float* b2 = (const float*)d_in[8];
  const float* W3 = (const float*)d_in[9];
  const float* g3 = (const float*)d_in[10];
  const float* b3 = (const float*)d_in[11];
  float* out = (float*)d_out;

  char* w = (char*)d_ws;
  float* allx = (float*)(w + OFF_ALLX);
  float* newx = (float*)(w + OFF_NEWX);
  int* inds_i = (int*)(w + OFF_INDSI);
  int* idx = (int*)(w + OFF_IDX);
  float* stats = (float*)(w + OFF_STATS);
  float* s1sum = stats, *s1sq = stats + 8192;
  float* s2sum = stats + 16384, *s2sq = stats + 24576;
  float* s3sum = stats + 32768, *s3sq = stats + 49152;
  float* bn = (float*)(w + OFF_BN);
  float* bn1s = bn, *bn1h = bn + 128;
  float* bn2s = bn + 256, *bn2h = bn + 384;
  float* bn3s = bn + 512, *bn3h = bn + 768;
  float* maxz = (float*)(w + OFF_MAXZ);
  float* minz = (float*)(w + OFF_MINZ);
  __hip_bfloat16* zp = (__hip_bfloat16*)(w + OFF_ZP);
  int* hist = (int*)(w + OFF_HIST);
  int* offs = (int*)(w + OFF_OFFS);
  float* sxp = (float*)(w + OFF_SX);
  float* syp = (float*)(w + OFF_SY);
  float* szp = (float*)(w + OFF_SZ);
  int* sidx = (int*)(w + OFF_SIDX);
  float4* xyz4 = (float4*)(w + OFF_XYZ4);

  hipMemsetAsync(hist, 0, NB * 512 * sizeof(int), stream);
  k_build<<<(NB * P_ALL * 3 + 255) / 256, 256, 0, stream>>>(fixed, xyz, allx, newx, stats, inds_i, hist, xyz4);
  k_scan<<<NB, 512, 0, stream>>>(hist, offs);
  k_scatter<<<NB * N_PTS / 256, 256, 0, stream>>>(xyz4, offs, sxp, syp, szp, sidx);
  // fused FPS (blocks 0..NB-1) + zp tiles (blocks NB..NB+NB*ZPB-1)
  k_fps<<<NB + NB * ZPB, 1024, 0, stream>>>(xyz4, sxp, syp, szp, sidx, newx, inds_i,
                                            feats, W1, zp);
  // fused ball query + BN1 stats
  k_ball<<<(NB * S_TOT) / 4, 256, 0, stream>>>(allx, newx, W1, zp, idx, s1sum, s1sq);
  k_fin<<<1, 256, 0, stream>>>(s1sum, s1sq, g1, b1, bn1s, bn1h, 128);
  k_layer2s<<<NB * S_TOT, 256, 0, stream>>>(idx, allx, newx, W1, zp, bn1s, bn1h, W2, s2sum, s2sq);
  k_fin<<<1, 256, 0, stream>>>(s2sum, s2sq, g2, b2, bn2s, bn2h, 128);
  k_layer3<<<NB * S_TOT, 256, 0, stream>>>(idx, allx, newx, W1, zp, bn1s, bn1h, W2,
                                           bn2s, bn2h, W3, maxz, minz, s3sum, s3sq);
  k_fin<<<1, 256, 0, stream>>>(s3sum, s3sq, g3, b3, bn3s, bn3h, 256);
  k_final<<<NB * S_TOT, 256, 0, stream>>>(maxz, minz, bn3s, bn3h, out);
  k_copy<<<(NB * S_TOT * 3 + NB * NPT + 255) / 256, 256, 0, stream>>>(newx, inds_i, out);
}

// Round 17
// 4175.713 us; speedup vs baseline: 1.5659x; 1.5659x over previous
//
#include <hip/hip_runtime.h>
#include <hip/hip_bf16.h>
#include <cstdint>
#include <cstddef>

#define NB 4
#define N_PTS 16384
#define M_FIX 256
#define P_ALL 16640
#define S_TOT 2304
#define NPT 2048
#define KNB 64
#define CH1 128
#define CH3 256
#define NRED 589824.0f
#define ZPB (P_ALL / 64)   // 260 zp tiles per batch

typedef float v2f __attribute__((ext_vector_type(2)));

// d_out offsets (float elements)
#define OUT_XYZ 0
#define OUT_FEAT 27648
#define OUT_INDS 2386944

// workspace offsets (bytes) -- total 39,481,344 B (~37.7 MB)
#define OFF_ALLX   0ull           // 4*16640*3*4 = 798720
#define OFF_STATS  798720ull      // 65536*4     = 262144
#define OFF_BN     1060864ull     // 1024*4      = 4096
#define OFF_MAXZ   1064960ull     // 9437184
#define OFF_MINZ   10502144ull    // 9437184
#define OFF_IDX    19939328ull    // 4*2304*64*4 = 2359296
#define OFF_ZP     22298624ull    // bf16 4*16640*128*2 = 17039360
#define OFF_NEWX   39337984ull    // 4*2304*3*4  = 110592
#define OFF_INDSI  39448576ull    // 4*2048*4    = 32768
// FPS scratch OVERLAPS the maxz region (maxz only written by k_layer3,
// long after k_fps finishes):
#define OFF_HIST   1064960ull     // 4*512*4 = 8192
#define OFF_OFFS   1073152ull     // 8192
#define OFF_SX     1081344ull     // 4*16384*4 = 262144
#define OFF_SY     1343488ull
#define OFF_SZ     1605632ull
#define OFF_SIDX   1867776ull     // end 2129920
#define OFF_XYZ4   2129920ull     // 4*16384*16 = 1048576, end 3178496 (< maxz end)

// ---------------------------------------------------------------- helpers
__device__ __forceinline__ float red16s(float v) {
  v += __shfl_xor(v, 1); v += __shfl_xor(v, 2);
  v += __shfl_xor(v, 4); v += __shfl_xor(v, 8);
  return v;
}
__device__ __forceinline__ float red16mx(float v) {
  v = fmaxf(v, __shfl_xor(v, 1)); v = fmaxf(v, __shfl_xor(v, 2));
  v = fmaxf(v, __shfl_xor(v, 4)); v = fmaxf(v, __shfl_xor(v, 8));
  return v;
}
__device__ __forceinline__ float red16mn(float v) {
  v = fminf(v, __shfl_xor(v, 1)); v = fminf(v, __shfl_xor(v, 2));
  v = fminf(v, __shfl_xor(v, 4)); v = fminf(v, __shfl_xor(v, 8));
  return v;
}
__device__ __forceinline__ float xyzp(float dx, float dy, float dz,
                                      float wx, float wy, float wz) {
  return fmaf(dx, wx, fmaf(dy, wy, __fmul_rn(dz, wz)));
}
__device__ __forceinline__ int mort3(int v) {
  return (v & 1) | ((v & 2) << 1) | ((v & 4) << 2);
}
__device__ __forceinline__ int cell_code(float x, float y, float z) {
  int cx = min(7, max(0, (int)(x * 8.0f)));
  int cy = min(7, max(0, (int)(y * 8.0f)));
  int cz = min(7, max(0, (int)(z * 8.0f)));
  return mort3(cx) | (mort3(cy) << 1) | (mort3(cz) << 2);
}

// u64 max with a DPP-shifted copy (VALU-pipe latency, no LDS round-trip).
// bound_ctrl=false + old=self => masked/invalid lanes are identity for max.
template <int CTRL, int RM>
__device__ __forceinline__ unsigned long long dppmax(unsigned long long k) {
  int lo = (int)(unsigned)(k & 0xFFFFFFFFull);
  int hi = (int)(unsigned)(k >> 32);
  int sl = __builtin_amdgcn_update_dpp(lo, lo, CTRL, RM, 0xF, false);
  int sh = __builtin_amdgcn_update_dpp(hi, hi, CTRL, RM, 0xF, false);
  unsigned long long s = ((unsigned long long)(unsigned)sh << 32) | (unsigned)sl;
  return (s > k) ? s : k;
}
// full wave64 max-reduce -> valid in lane 63
__device__ __forceinline__ unsigned long long wave_max64(unsigned long long k) {
  k = dppmax<0x111, 0xF>(k);  // row_shr:1
  k = dppmax<0x112, 0xF>(k);  // row_shr:2
  k = dppmax<0x114, 0xF>(k);  // row_shr:4
  k = dppmax<0x118, 0xF>(k);  // row_shr:8
  k = dppmax<0x142, 0xa>(k);  // row_bcast:15 -> rows 1,3
  k = dppmax<0x143, 0xc>(k);  // row_bcast:31 -> rows 2,3
  return k;
}
// 16-lane row max-reduce -> valid in lane 15 of each row
__device__ __forceinline__ unsigned long long row_max64(unsigned long long k) {
  k = dppmax<0x111, 0xF>(k);
  k = dppmax<0x112, 0xF>(k);
  k = dppmax<0x114, 0xF>(k);
  k = dppmax<0x118, 0xF>(k);
  return k;
}

// ---------------------------------------------------------------- build arrays
// R13: k_cell folded in (hist zeroed by hipMemsetAsync before this dispatch).
__global__ void k_build(const float* __restrict__ fixed, const float* __restrict__ xyz,
                        float* __restrict__ allx, float* __restrict__ newx,
                        float* __restrict__ stats, int* __restrict__ inds_i,
                        int* __restrict__ hist, float4* __restrict__ xyz4) {
  int i = blockIdx.x * 256 + threadIdx.x;
  if (i < NB * P_ALL * 3) {
    int b = i / (P_ALL * 3);
    int r = i % (P_ALL * 3);
    int p = r / 3, c = r % 3;
    float v = (p < M_FIX) ? fixed[((size_t)b * M_FIX + p) * 3 + c]
                          : xyz[((size_t)b * N_PTS + (p - M_FIX)) * 3 + c];
    allx[i] = v;
  }
  if (i < NB * N_PTS) {
    const float* pt = xyz + (size_t)i * 3;
    float x = pt[0], y = pt[1], z = pt[2];
    xyz4[i] = make_float4(x, y, z, 0.f);
    int b = i >> 14;
    int code = cell_code(x, y, z);
    atomicAdd(&hist[(b << 9) + code], 1);
  }
  if (i < NB * M_FIX * 3) {
    int b = i / (M_FIX * 3);
    int r = i % (M_FIX * 3);
    newx[(size_t)b * S_TOT * 3 + r] = fixed[(size_t)b * M_FIX * 3 + r];
  }
  if (i < 65536) stats[i] = 0.0f;
  if (i < NB) inds_i[(size_t)i * NPT] = 0;
}

__global__ __launch_bounds__(512) void k_scan(const int* __restrict__ hist,
                                              int* __restrict__ offs) {
  __shared__ int tmp[512];
  int b = blockIdx.x, t = threadIdx.x;
  int h = hist[(b << 9) + t];
  tmp[t] = h;
  __syncthreads();
  for (int o = 1; o < 512; o <<= 1) {
    int v = (t >= o) ? tmp[t - o] : 0;
    __syncthreads();
    tmp[t] += v;
    __syncthreads();
  }
  offs[(b << 9) + t] = tmp[t] - h;  // exclusive
}

// R13: reads coalesced xyz4 (bit-identical values).
__global__ void k_scatter(const float4* __restrict__ xyz4, int* __restrict__ offs,
                          float* __restrict__ sx, float* __restrict__ sy,
                          float* __restrict__ sz, int* __restrict__ sidx) {
  int i = blockIdx.x * 256 + threadIdx.x;
  int b = i >> 14, p = i & 16383;
  float4 pt = xyz4[i];
  float x = pt.x, y = pt.y, z = pt.z;
  int code = cell_code(x, y, z);
  int pos = atomicAdd(&offs[(b << 9) + code], 1);
  int o = (b << 14) + pos;
  sx[o] = x; sy[o] = y; sz[o] = z; sidx[o] = p;
}

// ---------------------------------------------------------------- FPS + zp (fused)
// FPS path: R10/R8 two-barrier shape, permanently frozen. zp fused (R10 win).
// R17: stride back to 132 (R13 champion). R15/R16 ATTRIBUTION: WTS=133 (odd)
// broke the 16B alignment of the float4 w_t reads (byte offset 532c == 4 mod
// 16 for odd c) => misaligned ds_read_b128 slow path, ~4x layer slowdown.
// Stride must stay a multiple of 4 floats. The zp-path's 4-way write
// conflicts (1.6M/dispatch) are benign -- zp is hidden under FPS (R13: 4193).
__global__ __launch_bounds__(1024, 4) void k_fps(const float4* __restrict__ xyz4,
                                                 const float* __restrict__ sx,
                                                 const float* __restrict__ sy,
                                                 const float* __restrict__ sz,
                                                 const int* __restrict__ sidx,
                                                 float* __restrict__ newx,
                                                 int* __restrict__ inds_i,
                                                 const float* __restrict__ feats,
                                                 const float* __restrict__ W1,
                                                 __hip_bfloat16* __restrict__ zp) {
  __shared__ __align__(16) float smem[CH1 * 68 + 32 * 132];  // 51712 B
  int t = threadIdx.x;

  if (blockIdx.x >= NB) {
    // ---------------- zp path: one 64-point tile, 1024 threads ----------------
    int bz = blockIdx.x - NB;
    int b = bz / ZPB;
    int p0 = (bz % ZPB) * 64;
    float* a_t = smem;
    float* w_t = smem + CH1 * 68;
    for (int r = t; r < CH1 * 64; r += 1024) {
      int c = r >> 6, p = r & 63;
      a_t[c * 68 + p] = feats[((size_t)b * CH1 + c) * P_ALL + p0 + p];
    }
    int tk = t & 63, to = t >> 6;  // point row 0..63, output group 0..15
    v2f acc[4];
#pragma unroll
    for (int p = 0; p < 4; ++p) acc[p] = (v2f){0.f, 0.f};
    const float* Wg = W1 + 3;  // ldw 131
    for (int c0 = 0; c0 < CH1; c0 += 32) {
      __syncthreads();  // first iter: a_t staged; later: prev compute done
      for (int r = t; r < 32 * 128; r += 1024) {
        int c = r & 31, o = r >> 5;  // c-major: coalesced W rows
        w_t[c * 132 + o] = Wg[(size_t)o * 131 + (c0 + c)];
      }
      __syncthreads();
#pragma unroll 4
      for (int c = 0; c < 32; ++c) {
        float a = a_t[(c0 + c) * 68 + tk];       // lane-striped, 2-way free
        v2f w2[4];                               // wave-uniform broadcast reads
        *(float4*)&w2[0] = *(const float4*)&w_t[c * 132 + to * 8];
        *(float4*)&w2[2] = *(const float4*)&w_t[c * 132 + to * 8 + 4];
        v2f a2 = {a, a};
#pragma unroll
        for (int p = 0; p < 4; ++p)
          acc[p] = __builtin_elementwise_fma(a2, w2[p], acc[p]);
      }
    }
    union { __hip_bfloat16 h[8]; uint4 u; } tmp;
#pragma unroll
    for (int j = 0; j < 8; ++j)
      tmp.h[j] = __float2bfloat16((j & 1) ? acc[j >> 1].y : acc[j >> 1].x);
    *(uint4*)&zp[((size_t)b * P_ALL + p0 + tk) * CH1 + to * 8] = tmp.u;
    return;
  }

  // ---------------- FPS path (blocks 0..NB-1), R10/R8 two-barrier shape ------
  unsigned long long* red = (unsigned long long*)smem;     // 16 u64
  float4* wcoord = (float4*)(smem + 32);                   // 16 float4
  float4* s_win = (float4*)(smem + 96);                    // 1 float4
  int* idxbuf = (int*)(smem + 100);                        // NPT ints

  int b = blockIdx.x;
  const float4* bx4 = xyz4 + (size_t)b * N_PTS;
  int off0 = (b << 14) + (t << 4);
  v2f px2[8], py2[8], pz2[8];
  float dist[16];
  unsigned npidp[8];  // packed 16-bit keys: 16383 - orig_idx
#pragma unroll
  for (int u = 0; u < 8; ++u) {
    px2[u] = *(const v2f*)&sx[off0 + 2 * u];
    py2[u] = *(const v2f*)&sy[off0 + 2 * u];
    pz2[u] = *(const v2f*)&sz[off0 + 2 * u];
    dist[2 * u] = 1e10f; dist[2 * u + 1] = 1e10f;
  }
#pragma unroll
  for (int u = 0; u < 8; ++u) {
    unsigned a = 16383u - (unsigned)sidx[off0 + 2 * u];
    unsigned c = 16383u - (unsigned)sidx[off0 + 2 * u + 1];
    npidp[u] = a | (c << 16);
  }
  float xmn = px2[0].x, xmx = px2[0].x, ymn = py2[0].x, ymx = py2[0].x;
  float zmn = pz2[0].x, zmx = pz2[0].x;
#pragma unroll
  for (int u = 0; u < 8; ++u) {
    xmn = fminf(xmn, fminf(px2[u].x, px2[u].y));
    xmx = fmaxf(xmx, fmaxf(px2[u].x, px2[u].y));
    ymn = fminf(ymn, fminf(py2[u].x, py2[u].y));
    ymx = fmaxf(ymx, fmaxf(py2[u].x, py2[u].y));
    zmn = fminf(zmn, fminf(pz2[u].x, pz2[u].y));
    zmx = fmaxf(zmx, fmaxf(pz2[u].x, pz2[u].y));
  }
  float cx = (xmn + xmx) * 0.5f, cy = (ymn + ymx) * 0.5f, cz = (zmn + zmx) * 0.5f;
  float r2m = 0.f;
#pragma unroll
  for (int u = 0; u < 8; ++u) {
#pragma unroll
    for (int h = 0; h < 2; ++h) {
      float ax = (h ? px2[u].y : px2[u].x) - cx;
      float ay = (h ? py2[u].y : py2[u].x) - cy;
      float az = (h ? pz2[u].y : pz2[u].x) - cz;
      r2m = fmaxf(r2m, ax * ax + ay * ay + az * az);
    }
  }
  float rad = sqrtf(r2m) + 2e-3f;  // slack >> fp32 rounding
  float4 p0 = bx4[0];
  float lx = p0.x, ly = p0.y, lz = p0.z;
  if (t == 0) {
    size_t nb0 = ((size_t)b * S_TOT + M_FIX) * 3;
    newx[nb0] = lx; newx[nb0 + 1] = ly; newx[nb0 + 2] = lz;
  }
  unsigned long long bestkey = 0ull;
  unsigned long long kprev = ~0ull;  // sentinel: never equals a real key
  float thr = 3.4e38f;  // first iteration: everyone active
  int lane = t & 63, wid = t >> 6;
  for (int iter = 1; iter < NPT; ++iter) {
    float ex = lx - cx, ey = ly - cy, ez = lz - cz;
    bool active = (ex * ex + ey * ey + ez * ez) < thr;
    if (__ballot(active) != 0ull) {  // wave-uniform
      // pass 1: exact distance update + per-thread change flag.
      bool ch = false;
      if (active) {
#pragma clang fp contract(off)
        v2f l2x = {lx, lx}, l2y = {ly, ly}, l2z = {lz, lz};
#pragma unroll
        for (int u = 0; u < 8; ++u) {
          v2f dx = px2[u] - l2x;
          v2f dy = py2[u] - l2y;
          v2f dz = pz2[u] - l2z;
          v2f xx = dx * dx;
          v2f yy = dy * dy;
          v2f zz = dz * dz;
          v2f d2 = (xx + yy) + zz;
          if (d2.x < dist[2 * u])     { dist[2 * u] = d2.x;     ch = true; }
          if (d2.y < dist[2 * u + 1]) { dist[2 * u + 1] = d2.y; ch = true; }
        }
      }
      // pass 2: key rebuild + reduce, only if some lane actually changed.
      // Skipped => bestkey/thr/red[wid]/wcoord[wid] all provably unchanged.
      if (__ballot(ch) != 0ull) {  // wave-uniform
        if (ch) {
          unsigned long long c0 = 0ull, c1 = 0ull, c2 = 0ull, c3 = 0ull;
#pragma unroll
          for (int j = 0; j < 16; ++j) {
            unsigned lo16 = (j & 1) ? (npidp[j >> 1] >> 16) : (npidp[j >> 1] & 0xFFFFu);
            unsigned long long kj =
                ((unsigned long long)__float_as_uint(dist[j]) << 32) | lo16;
            if ((j & 3) == 0) c0 = (kj > c0) ? kj : c0;
            else if ((j & 3) == 1) c1 = (kj > c1) ? kj : c1;
            else if ((j & 3) == 2) c2 = (kj > c2) ? kj : c2;
            else c3 = (kj > c3) ? kj : c3;
          }
          c0 = (c1 > c0) ? c1 : c0;
          c2 = (c3 > c2) ? c3 : c2;
          bestkey = (c2 > c0) ? c2 : c0;
          float ub = __uint_as_float((unsigned)(bestkey >> 32));
          float tq = sqrtf(ub) + rad;
          thr = tq * tq;
        }
        unsigned long long k = wave_max64(bestkey);
        unsigned long long kall = __shfl(k, 63);
        // Owner resolves coords into the per-wave LDS slot only when the
        // wave's max actually changed (kall wave-uniform => uniform branch).
        if (kall != kprev) {
          if (bestkey == kall) {
            unsigned lo = (unsigned)(kall & 0xFFFFull);
            float wx = 0.f, wy = 0.f, wz = 0.f;
#pragma unroll
            for (int u = 0; u < 8; ++u) {
              unsigned pk = npidp[u];
              if ((pk & 0xFFFFu) == lo) { wx = px2[u].x; wy = py2[u].x; wz = pz2[u].x; }
              if ((pk >> 16) == lo)     { wx = px2[u].y; wy = py2[u].y; wz = pz2[u].y; }
            }
            wcoord[wid] = make_float4(wx, wy, wz, 0.f);
          }
          kprev = kall;
        }
        if (lane == 63) red[wid] = k;
      }
    }
    __syncthreads();
    if (wid == 0) {
      unsigned long long wk = red[lane & 15];
      unsigned long long wr = row_max64(wk);
      unsigned long long wmax = __shfl(wr, 15);
      unsigned long long mb = __ballot(wk == wmax) & 0xFFFFull;
      int src = __ffsll(mb) - 1;  // unique (keys unique)
      if (lane == 15) {
        *s_win = wcoord[src];
        idxbuf[iter] = 16383 - (int)(wmax & 0xFFFFull);
      }
    }
    __syncthreads();
    float4 wv = *s_win;
    lx = wv.x; ly = wv.y; lz = wv.z;
  }
  __syncthreads();
  for (int s = t; s < NPT; s += 1024) {
    if (s == 0) continue;
    int wi = idxbuf[s];
    float4 wp = bx4[wi];
    inds_i[(size_t)b * NPT + s] = wi;
    size_t nb2 = ((size_t)b * S_TOT + M_FIX + s) * 3;
    newx[nb2] = wp.x; newx[nb2 + 1] = wp.y; newx[nb2 + 2] = wp.z;
  }
}

// ---------------------------------------------------------------- ball query + BN1 stats (fused)
// R12: stats1 fused (WIN). Even/odd-k partial sums kept separate and added
// once at the end -- exactly reproduces stats1's two-group reduction =>
// bit-identical atomicAdd addends.
__global__ __launch_bounds__(256) void k_ball(const float* __restrict__ allx,
                                              const float* __restrict__ newx,
                                              const float* __restrict__ W1,
                                              const __hip_bfloat16* __restrict__ zp,
                                              int* __restrict__ idx,
                                              float* __restrict__ sSum,
                                              float* __restrict__ sSq) {
  __shared__ int s_pid[4][KNB];
  int wid = threadIdx.x >> 6, lane = threadIdx.x & 63;
  int q = blockIdx.x * 4 + wid;  // 0..9215
  int b = q / S_TOT;
  const float* qp = newx + (size_t)q * 3;
  float qx = qp[0], qy = qp[1], qz = qp[2];
  const float* pts = allx + (size_t)b * P_ALL * 3;
  int* outp = idx + (size_t)q * KNB;
  const float R2 = 0.04f;
  int collected = 0;
  int first_hit = 0;
  for (int ch = 0; ch < P_ALL / 64; ++ch) {
    int p = ch * 64 + lane;
    float x = pts[p * 3 + 0], y = pts[p * 3 + 1], z = pts[p * 3 + 2];
    float dx = __fsub_rn(qx, x), dy = __fsub_rn(qy, y), dz = __fsub_rn(qz, z);
    float d2 = __fadd_rn(__fadd_rn(__fmul_rn(dx, dx), __fmul_rn(dy, dy)), __fmul_rn(dz, dz));
    bool hit = d2 < R2;
    unsigned long long m = __ballot(hit);
    if (m) {
      if (collected == 0) first_hit = ch * 64 + (__ffsll((unsigned long long)m) - 1);
      if (hit) {
        int slot = collected + __popcll(m & ((1ull << lane) - 1ull));
        if (slot < KNB) { outp[slot] = p; s_pid[wid][slot] = p; }
      }
      collected += __popcll(m);
      if (collected >= KNB) break;
    }
  }
  int sl = collected + lane;
  if (sl < KNB) { outp[sl] = first_hit; s_pid[wid][sl] = first_hit; }

  // ---- fused BN1 stats ----
  int c0 = 2 * lane, c1 = 2 * lane + 1;
  float wx0 = W1[(size_t)c0 * 131 + 0], wy0 = W1[(size_t)c0 * 131 + 1],
        wz0 = W1[(size_t)c0 * 131 + 2];
  float wx1 = W1[(size_t)c1 * 131 + 0], wy1 = W1[(size_t)c1 * 131 + 1],
        wz1 = W1[(size_t)c1 * 131 + 2];
  const uint16_t* zpb = (const uint16_t*)zp + (size_t)b * P_ALL * CH1;
  float se0 = 0.f, so0 = 0.f, se1 = 0.f, so1 = 0.f;
  float se0q = 0.f, so0q = 0.f, se1q = 0.f, so1q = 0.f;
#pragma unroll 2
  for (int k = 0; k < KNB; ++k) {
    int pid = s_pid[wid][k];
    const float* pp = pts + (size_t)pid * 3;
    float dxk = __fmul_rn(__fsub_rn(pp[0], qx), 5.0f);
    float dyk = __fmul_rn(__fsub_rn(pp[1], qy), 5.0f);
    float dzk = __fmul_rn(__fsub_rn(pp[2], qz), 5.0f);
    uint32_t w = *(const uint32_t*)(zpb + (size_t)pid * CH1 + c0);
    float v0 = __uint_as_float(w << 16);
    float v1 = __uint_as_float(w & 0xFFFF0000u);
    v0 += xyzp(dxk, dyk, dzk, wx0, wy0, wz0);
    v1 += xyzp(dxk, dyk, dzk, wx1, wy1, wz1);
    if (k & 1) {
      so0 += v0; so0q = fmaf(v0, v0, so0q);
      so1 += v1; so1q = fmaf(v1, v1, so1q);
    } else {
      se0 += v0; se0q = fmaf(v0, v0, se0q);
      se1 += v1; se1q = fmaf(v1, v1, se1q);
    }
  }
  int slot = q & 63;
  atomicAdd(&sSum[slot * CH1 + c0], se0 + so0);
  atomicAdd(&sSq[slot * CH1 + c0], se0q + so0q);
  atomicAdd(&sSum[slot * CH1 + c1], se1 + so1);
  atomicAdd(&sSq[slot * CH1 + c1], se1q + so1q);
}

// ---------------------------------------------------------------- GEMM helper
// block tile: 64(k) x 128(o), 256 threads = 16(tk) x 16(to), 4x8 regs/thread.
// R9: packed v_pk_fma_f32 accumulators (bit-identical).
// R13: W staging c-major (coalesced: 2 cache lines/wave-load vs 64). WIN.
// R17: stride kept at 132 (multiple of 4 floats => float4 reads 16B-aligned).
// R14-R16 lessons: odd stride 133 breaks read alignment (~4x slowdown);
// register-staged prefetch spills (wr[16] live across unrolled FMA loop).
__device__ __forceinline__ void gemm_chunks(const float* a_t, float* w_t,
                                            const float* __restrict__ Wg, int K,
                                            int obase, int ldw, int tid,
                                            v2f acc[4][4]) {
  int tk = tid & 15, to = tid >> 4;
  for (int c0 = 0; c0 < K; c0 += 32) {
    __syncthreads();
    for (int r = tid; r < 32 * 128; r += 256) {
      int c = r & 31, o = r >> 5;
      w_t[c * 132 + o] = Wg[(size_t)(obase + o) * ldw + (c0 + c)];
    }
    __syncthreads();
#pragma unroll 4
    for (int c = 0; c < 32; ++c) {
      float a4[4];
      v2f w2[4];
      *(float4*)a4 = *(const float4*)&a_t[(c0 + c) * 68 + tk * 4];
      *(float4*)&w2[0] = *(const float4*)&w_t[c * 132 + to * 8];
      *(float4*)&w2[2] = *(const float4*)&w_t[c * 132 + to * 8 + 4];
#pragma unroll
      for (int i = 0; i < 4; ++i) {
        v2f a2 = {a4[i], a4[i]};
#pragma unroll
        for (int p = 0; p < 4; ++p)
          acc[i][p] = __builtin_elementwise_fma(a2, w2[p], acc[i][p]);
      }
    }
  }
}
// extract output j (0..7) of row i from the packed accumulator
#define ACC_J(acc, i, j) (((j) & 1) ? acc[i][(j) >> 1].y : acc[i][(j) >> 1].x)

// ---------------------------------------------------------------- geometry staging
__device__ __forceinline__ void stage_geom(int bs, int b, const int* __restrict__ idxg,
                                           const float* __restrict__ allx,
                                           const float* __restrict__ newx,
                                           const float* __restrict__ W1,
                                           int* s_pid, float* s_d, float* s_w1, int tid) {
  if (tid < 64) {
    int p = idxg[(size_t)bs * KNB + tid];
    s_pid[tid] = p;
    const float* pp = allx + ((size_t)b * P_ALL + p) * 3;
    const float* qq = newx + (size_t)bs * 3;
    s_d[tid]       = __fmul_rn(__fsub_rn(pp[0], qq[0]), 5.0f);
    s_d[64 + tid]  = __fmul_rn(__fsub_rn(pp[1], qq[1]), 5.0f);
    s_d[128 + tid] = __fmul_rn(__fsub_rn(pp[2], qq[2]), 5.0f);
  } else if (tid < 192) {
    int c = tid - 64;
    s_w1[c]       = W1[(size_t)c * 131 + 0];
    s_w1[128 + c] = W1[(size_t)c * 131 + 1];
    s_w1[256 + c] = W1[(size_t)c * 131 + 2];
  }
  __syncthreads();
}

// ---------------------------------------------------------------- a1 build
// R9 lane remap (k=tid&63, q=tid>>6): conflict-free a_t writes, wave-uniform
// s_w1 reads. Bit-identical a_t.
__device__ __forceinline__ void build_a1(float* a_t, const int* s_pid, const float* s_d,
                                         const float* s_w1,
                                         const __hip_bfloat16* __restrict__ zp_b,
                                         const float* __restrict__ bnS,
                                         const float* __restrict__ bnH, int tid) {
  int k = tid & 63, q = tid >> 6;
  int pid = s_pid[k];
  float dx = s_d[k], dy = s_d[64 + k], dz = s_d[128 + k];
  const uint32_t* zr = (const uint32_t*)((const uint16_t*)zp_b + (size_t)pid * CH1 + q * 32);
#pragma unroll
  for (int u = 0; u < 16; ++u) {
    uint32_t w = zr[u];
    int c = q * 32 + u * 2;
    float v0 = __uint_as_float(w << 16);
    float v1 = __uint_as_float(w & 0xFFFF0000u);
    v0 += xyzp(dx, dy, dz, s_w1[c], s_w1[128 + c], s_w1[256 + c]);
    v1 += xyzp(dx, dy, dz, s_w1[c + 1], s_w1[128 + c + 1], s_w1[256 + c + 1]);
    a_t[c * 68 + k]       = fmaxf(fmaf(v0, bnS[c], bnH[c]), 0.0f);
    a_t[(c + 1) * 68 + k] = fmaxf(fmaf(v1, bnS[c + 1], bnH[c + 1]), 0.0f);
  }
}

// ---------------------------------------------------------------- layer 2 (stats only)
__global__ __launch_bounds__(256) void k_layer2s(const int* __restrict__ idxg,
                                                 const float* __restrict__ allx,
                                                 const float* __restrict__ newx,
                                                 const float* __restrict__ W1,
                                                 const __hip_bfloat16* __restrict__ zp,
                                                 const float* __restrict__ bn1S,
                                                 const float* __restrict__ bn1H,
                                                 const float* __restrict__ W2,
                                                 float* __restrict__ sSum,
                                                 float* __restrict__ sSq) {
  __shared__ __align__(16) float smem[CH1 * 68 + 32 * 132];
  float* a_t = smem;
  float* w_t = smem + CH1 * 68;
  int* s_pid = (int*)w_t;
  float* s_d = w_t + 64;
  float* s_w1 = w_t + 256;
  int bs = blockIdx.x;
  int b = bs / S_TOT;
  int tid = threadIdx.x;
  stage_geom(bs, b, idxg, allx, newx, W1, s_pid, s_d, s_w1, tid);
  build_a1(a_t, s_pid, s_d, s_w1, zp + (size_t)b * P_ALL * CH1, bn1S, bn1H, tid);
  v2f acc[4][4];
#pragma unroll
  for (int i = 0; i < 4; ++i)
#pragma unroll
    for (int p = 0; p < 4; ++p) acc[i][p] = (v2f){0.f, 0.f};
  gemm_chunks(a_t, w_t, W2, CH1, 0, CH1, tid, acc);
  int tk = tid & 15, to = tid >> 4;
  int slot = bs & 63;
#pragma unroll
  for (int j = 0; j < 8; ++j) {
    float s1 = 0.f, s2 = 0.f;
#pragma unroll
    for (int i = 0; i < 4; ++i) { float v = ACC_J(acc, i, j); s1 += v; s2 = fmaf(v, v, s2); }
    s1 = red16s(s1);
    s2 = red16s(s2);
    if (tk == 0) {
      int o = to * 8 + j;
      atomicAdd(&sSum[slot * CH1 + o], s1);
      atomicAdd(&sSq[slot * CH1 + o], s2);
    }
  }
}

// ---------------------------------------------------------------- layer 3
__global__ __launch_bounds__(256) void k_layer3(const int* __restrict__ idxg,
                                                const float* __restrict__ allx,
                                                const float* __restrict__ newx,
                                                const float* __restrict__ W1,
                                                const __hip_bfloat16* __restrict__ zp,
                                                const float* __restrict__ bn1S,
                                                const float* __restrict__ bn1H,
                                                const float* __restrict__ W2,
                                                const float* __restrict__ bn2S,
                                                const float* __restrict__ bn2H,
                                                const float* __restrict__ W3,
                                                float* __restrict__ maxz,
                                                float* __restrict__ minz,
                                                float* __restrict__ sSum,
                                                float* __restrict__ sSq) {
  __shared__ __align__(16) float smem[CH1 * 68 + 32 * 132];
  float* a_t = smem;
  float* w_t = smem + CH1 * 68;
  int* s_pid = (int*)w_t;
  float* s_d = w_t + 64;
  float* s_w1 = w_t + 256;
  int bs = blockIdx.x;
  int b = bs / S_TOT;
  int tid = threadIdx.x;
  stage_geom(bs, b, idxg, allx, newx, W1, s_pid, s_d, s_w1, tid);
  build_a1(a_t, s_pid, s_d, s_w1, zp + (size_t)b * P_ALL * CH1, bn1S, bn1H, tid);
  v2f acc[4][4];
#pragma unroll
  for (int i = 0; i < 4; ++i)
#pragma unroll
    for (int p = 0; p < 4; ++p) acc[i][p] = (v2f){0.f, 0.f};
  gemm_chunks(a_t, w_t, W2, CH1, 0, CH1, tid, acc);  // acc = z2 (bit-identical to k_layer2s)
  int tk = tid & 15, to = tid >> 4;
  __syncthreads();  // all a1 reads done before overwriting a_t with a2
#pragma unroll
  for (int j = 0; j < 8; ++j) {
    int o = to * 8 + j;
    float sc = bn2S[o], sh = bn2H[o];
#pragma unroll
    for (int i = 0; i < 4; ++i)
      a_t[o * 68 + tk * 4 + i] = fmaxf(fmaf(ACC_J(acc, i, j), sc, sh), 0.0f);
  }
  int slot = bs & 63;
#pragma unroll 1
  for (int half = 0; half < 2; ++half) {
    v2f acc3[4][4];
#pragma unroll
    for (int i = 0; i < 4; ++i)
#pragma unroll
      for (int p = 0; p < 4; ++p) acc3[i][p] = (v2f){0.f, 0.f};
    gemm_chunks(a_t, w_t, W3, CH1, half * 128, CH1, tid, acc3);
#pragma unroll
    for (int j = 0; j < 8; ++j) {
      float s1 = 0.f, s2 = 0.f, mx = -3.4e38f, mn = 3.4e38f;
#pragma unroll
      for (int i = 0; i < 4; ++i) {
        float v = ACC_J(acc3, i, j);
        s1 += v; s2 = fmaf(v, v, s2);
        mx = fmaxf(mx, v); mn = fminf(mn, v);
      }
      s1 = red16s(s1);
      s2 = red16s(s2);
      mx = red16mx(mx);
      mn = red16mn(mn);
      if (tk == 0) {
        int o = half * 128 + to * 8 + j;
        atomicAdd(&sSum[slot * CH3 + o], s1);
        atomicAdd(&sSq[slot * CH3 + o], s2);
        size_t base = (size_t)bs * CH3 + o;
        maxz[base] = mx;
        minz[base] = mn;
      }
    }
  }
}

// ---------------------------------------------------------------- finalize BN
__global__ void k_fin(const float* __restrict__ sSum, const float* __restrict__ sSq,
                      const float* __restrict__ gamma, const float* __restrict__ beta,
                      float* __restrict__ bnS, float* __restrict__ bnH, int C) {
  int o = threadIdx.x;
  if (o >= C) return;
  float s1 = 0.f, s2 = 0.f;
  for (int t = 0; t < 64; ++t) { s1 += sSum[t * C + o]; s2 += sSq[t * C + o]; }
  float mean = s1 / NRED;
  float var = fmaxf(s2 / NRED - mean * mean, 0.f);
  float inv = 1.0f / sqrtf(var + 1e-5f);
  float sc = gamma[o] * inv;
  bnS[o] = sc;
  bnH[o] = beta[o] - mean * sc;
}

// ---------------------------------------------------------------- final pool
__global__ __launch_bounds__(256) void k_final(const float* __restrict__ maxz,
                                               const float* __restrict__ minz,
                                               const float* __restrict__ bnS,
                                               const float* __restrict__ bnH,
                                               float* __restrict__ out) {
  int bs = blockIdx.x;
  int o = threadIdx.x;
  float sc = bnS[o], sh = bnH[o];
  size_t base = (size_t)bs * CH3 + o;
  float v = (sc >= 0.f) ? maxz[base] : minz[base];
  float r = fmaxf(fmaf(v, sc, sh), 0.f);
  int b = bs / S_TOT, s = bs % S_TOT;
  out[OUT_FEAT + ((size_t)b * CH3 + o) * S_TOT + s] = r;
}

// ---------------------------------------------------------------- copy xyz+inds to out (last)
__global__ void k_copy(const float* __restrict__ newx, const int* __restrict__ inds_i,
                       float* __restrict__ out) {
  int i = blockIdx.x * 256 + threadIdx.x;
  if (i < NB * S_TOT * 3) out[OUT_XYZ + i] = newx[i];
  else {
    int r = i - NB * S_TOT * 3;
    if (r < NB * NPT) out[OUT_INDS + r] = (float)inds_i[r];
  }
}

// ---------------------------------------------------------------- launch
extern "C" void kernel_launch(void* const* d_in, const int* in_sizes, int n_in,
                              void* d_out, int out_size, void* d_ws, size_t ws_size,
                              hipStream_t stream) {
  const float* fixed = (const float*)d_in[0];
  const float* xyz = (const float*)d_in[1];
  const float* feats = (const float*)d_in[2];
  const float* W1 = (const float*)d_in[3];
  const float* g1 = (const float*)d_in[4];
  const float* b1 = (const float*)d_in[5];
  const float* W2 = (const float*)d_in[6];
  const float* g2 = (const float*)d_in[7];
  const float* b2 = (const float*)d_in[8];
  const float* W3 = (const float*)d_in[9];
  const float* g3 = (const float*)d_in[10];
  const float* b3 = (const float*)d_in[11];
  float* out = (float*)d_out;

  char* w = (char*)d_ws;
  float* allx = (float*)(w + OFF_ALLX);
  float* newx = (float*)(w + OFF_NEWX);
  int* inds_i = (int*)(w + OFF_INDSI);
  int* idx = (int*)(w + OFF_IDX);
  float* stats = (float*)(w + OFF_STATS);
  float* s1sum = stats, *s1sq = stats + 8192;
  float* s2sum = stats + 16384, *s2sq = stats + 24576;
  float* s3sum = stats + 32768, *s3sq = stats + 49152;
  float* bn = (float*)(w + OFF_BN);
  float* bn1s = bn, *bn1h = bn + 128;
  float* bn2s = bn + 256, *bn2h = bn + 384;
  float* bn3s = bn + 512, *bn3h = bn + 768;
  float* maxz = (float*)(w + OFF_MAXZ);
  float* minz = (float*)(w + OFF_MINZ);
  __hip_bfloat16* zp = (__hip_bfloat16*)(w + OFF_ZP);
  int* hist = (int*)(w + OFF_HIST);
  int* offs = (int*)(w + OFF_OFFS);
  float* sxp = (float*)(w + OFF_SX);
  float* syp = (float*)(w + OFF_SY);
  float* szp = (float*)(w + OFF_SZ);
  int* sidx = (int*)(w + OFF_SIDX);
  float4* xyz4 = (float4*)(w + OFF_XYZ4);

  hipMemsetAsync(hist, 0, NB * 512 * sizeof(int), stream);
  k_build<<<(NB * P_ALL * 3 + 255) / 256, 256, 0, stream>>>(fixed, xyz, allx, newx, stats, inds_i, hist, xyz4);
  k_scan<<<NB, 512, 0, stream>>>(hist, offs);
  k_scatter<<<NB * N_PTS / 256, 256, 0, stream>>>(xyz4, offs, sxp, syp, szp, sidx);
  // fused FPS (blocks 0..NB-1) + zp tiles (blocks NB..NB+NB*ZPB-1)
  k_fps<<<NB + NB * ZPB, 1024, 0, stream>>>(xyz4, sxp, syp, szp, sidx, newx, inds_i,
                                            feats, W1, zp);
  // fused ball query + BN1 stats
  k_ball<<<(NB * S_TOT) / 4, 256, 0, stream>>>(allx, newx, W1, zp, idx, s1sum, s1sq);
  k_fin<<<1, 256, 0, stream>>>(s1sum, s1sq, g1, b1, bn1s, bn1h, 128);
  k_layer2s<<<NB * S_TOT, 256, 0, stream>>>(idx, allx, newx, W1, zp, bn1s, bn1h, W2, s2sum, s2sq);
  k_fin<<<1, 256, 0, stream>>>(s2sum, s2sq, g2, b2, bn2s, bn2h, 128);
  k_layer3<<<NB * S_TOT, 256, 0, stream>>>(idx, allx, newx, W1, zp, bn1s, bn1h, W2,
                                           bn2s, bn2h, W3, maxz, minz, s3sum, s3sq);
  k_fin<<<1, 256, 0, stream>>>(s3sum, s3sq, g3, b3, bn3s, bn3h, 256);
  k_final<<<NB * S_TOT, 256, 0, stream>>>(maxz, minz, bn3s, bn3h, out);
  k_copy<<<(NB * S_TOT * 3 + NB * NPT + 255) / 256, 256, 0, stream>>>(newx, inds_i, out);
}